// Round 18
// baseline (90.343 us; speedup 1.0000x reference)
//
#include <hip/hip_runtime.h>

#define LL 96
#define NT 256        // threads per block (4 waves)
#define BROWS 16      // batch rows staged per block
#define KPT 12        // k-cells per window (48B, 16B-aligned)
#define NI 3          // i-values per thread (stride 32): window reused 3x

__global__ __launch_bounds__(NT) void gl_loss_main(
    const float* __restrict__ yt, const float* __restrict__ yp,
    const float* __restrict__ w, float* __restrict__ out,
    int n, float inv_scale) {
  __shared__ __align__(16) float e_lds[BROWS][LL];  // 6 KB

  const int t  = threadIdx.x;
  const int ig = t >> 3;           // 0..31
  const int kc = t & 7;            // k-chunk
  const int k0 = kc * KPT;         // 4-aligned float offset

  // ---- weights -> registers for all 3 owned i-values (global, L2-hot) ----
  float w0r[NI][KPT], w1r[NI][KPT], w0d[NI], w1d[NI];
#pragma unroll
  for (int m = 0; m < NI; ++m) {
    int i = ig + 32 * m;
#pragma unroll
    for (int jj = 0; jj < KPT; ++jj) {
      int k = k0 + jj;
      bool valid = (k > i);                      // j = k-i >= 1 only
      w0r[m][jj] = valid ? w[i * LL + (k - i)] : 0.f;
      w1r[m][jj] = valid ? w[LL * LL + i * LL + (k - i)] : 0.f;
    }
    bool dg = (i >= k0) && (i < k0 + KPT);       // diagonal (j==0) owner
    w0d[m] = dg ? w[i * LL] : 0.f;
    w1d[m] = dg ? w[LL * LL + i * LL] : 0.f;
  }

  // ---- stage e = yt - yp as float4 (coalesced, 16B-aligned) ----
  const int b0 = blockIdx.x * BROWS;
  {
    float4* ef = (float4*)&e_lds[0][0];          // 384 float4
    for (int f = t; f < BROWS * LL / 4; f += NT) {
      int row = f / (LL / 4);
      int c4  = f - row * (LL / 4);
      int b = b0 + row;
      float4 v = make_float4(0.f, 0.f, 0.f, 0.f);
      if (b < n) {
        const float4 a = *(const float4*)&yt[b * LL + c4 * 4];
        const float4 p = *(const float4*)&yp[b * LL + c4 * 4];
        v = make_float4(a.x - p.x, a.y - p.y, a.z - p.z, a.w - p.w);
      }
      ef[f] = v;
    }
  }
  __syncthreads();

  // ---- inner loop: one k-window (3 b128) serves 3 i-values (3 b32) ----
  float acc0 = 0.f, acc1 = 0.f;
#pragma unroll 2
  for (int b = 0; b < BROWS; ++b) {
    float4 vA = *(const float4*)&e_lds[b][k0];
    float4 vB = *(const float4*)&e_lds[b][k0 + 4];
    float4 vC = *(const float4*)&e_lds[b][k0 + 8];
    float ek[KPT] = {vA.x, vA.y, vA.z, vA.w, vB.x, vB.y, vB.z, vB.w,
                     vC.x, vC.y, vC.z, vC.w};
#pragma unroll
    for (int m = 0; m < NI; ++m) {
      float ei = e_lds[b][ig + 32 * m];
#pragma unroll
      for (int jj = 0; jj < KPT; ++jj) {
        float d = fabsf(ei - ek[jj]);
        if (jj & 1)
          acc1 = fmaf(d, fmaf(d, w1r[m][jj], w0r[m][jj]), acc1);
        else
          acc0 = fmaf(d, fmaf(d, w1r[m][jj], w0r[m][jj]), acc0);
      }
      float a = fabsf(ei);                       // diagonal |e_i| term
      acc1 = fmaf(a, fmaf(a, w1d[m], w0d[m]), acc1);
    }
  }
  float acc = acc0 + acc1;

  // ---- reduce 256 threads -> ONE atomic direct to out (R13/R15-proven) ----
#pragma unroll
  for (int off = 32; off; off >>= 1) acc += __shfl_down(acc, off);
  __shared__ float wsum[NT / 64];
  if ((t & 63) == 0) wsum[t >> 6] = acc;
  __syncthreads();
  if (t == 0) {
    float s = wsum[0] + wsum[1] + wsum[2] + wsum[3];
    atomicAdd(out, s * inv_scale);
  }
}

extern "C" void kernel_launch(void* const* d_in, const int* in_sizes, int n_in,
                              void* d_out, int out_size, void* d_ws, size_t ws_size,
                              hipStream_t stream) {
  const float* yt = (const float*)d_in[0];
  const float* yp = (const float*)d_in[1];
  const float* w  = (const float*)d_in[2];
  float* out = (float*)d_out;
  int n = in_sizes[0] / LL;

  dim3 grid((n + BROWS - 1) / BROWS, 1);
  // Launch 1: the real computation (identical to R17).
  gl_loss_main<<<grid, NT, 0, stream>>>(yt, yp, w, out, n,
                                        1.0f / (float(LL) * float(n)));
  // Launch 2: TIMING PROBE — identical work, sinks into d_ws (write-only,
  // never read, does not touch d_out). dur_us delta vs R17 == T_main.
  gl_loss_main<<<grid, NT, 0, stream>>>(yt, yp, w, (float*)d_ws, n,
                                        1.0f / (float(LL) * float(n)));
}

// Round 20
// 72.305 us; speedup vs baseline: 1.2495x; 1.2495x over previous
//
#include <hip/hip_runtime.h>

#define LL 96
#define NT 256        // threads per block (4 waves)
#define BROWS 16      // batch rows staged per block
#define KPT 12        // k-cells per window (48B, 16B-aligned)
#define NI 3          // i-values per thread (stride 32): window reused 3x
#define NP 6          // float2 pairs per window

typedef float f32x2 __attribute__((ext_vector_type(2)));

__global__ __launch_bounds__(NT) void gl_loss_main(
    const float* __restrict__ yt, const float* __restrict__ yp,
    const float* __restrict__ w, float* __restrict__ out,
    int n, float inv_scale) {
  __shared__ __align__(16) float e_lds[BROWS][LL];  // 6 KB

  const int t  = threadIdx.x;
  const int ig = t >> 3;           // 0..31
  const int kc = t & 7;            // k-chunk
  const int k0 = kc * KPT;         // 4-aligned float offset

  // ---- weights -> packed f32x2 registers for all 3 owned i-values ----
  f32x2 w0v[NI][NP], w1v[NI][NP];
  float w0d[NI], w1d[NI];
#pragma unroll
  for (int m = 0; m < NI; ++m) {
    int i = ig + 32 * m;
#pragma unroll
    for (int jj = 0; jj < KPT; ++jj) {
      int k = k0 + jj;
      bool valid = (k > i);                      // j = k-i >= 1 only
      float a0 = valid ? w[i * LL + (k - i)] : 0.f;
      float a1 = valid ? w[LL * LL + i * LL + (k - i)] : 0.f;
      w0v[m][jj >> 1][jj & 1] = a0;
      w1v[m][jj >> 1][jj & 1] = a1;
    }
    bool dg = (i >= k0) && (i < k0 + KPT);       // diagonal (j==0) owner
    w0d[m] = dg ? w[i * LL] : 0.f;
    w1d[m] = dg ? w[LL * LL + i * LL] : 0.f;
  }

  // ---- stage e = yt - yp as float4 (coalesced, 16B-aligned) ----
  const int b0 = blockIdx.x * BROWS;
  {
    float4* ef = (float4*)&e_lds[0][0];          // 384 float4
    for (int f = t; f < BROWS * LL / 4; f += NT) {
      int row = f / (LL / 4);
      int c4  = f - row * (LL / 4);
      int b = b0 + row;
      float4 v = make_float4(0.f, 0.f, 0.f, 0.f);
      if (b < n) {
        const float4 a = *(const float4*)&yt[b * LL + c4 * 4];
        const float4 p = *(const float4*)&yp[b * LL + c4 * 4];
        v = make_float4(a.x - p.x, a.y - p.y, a.z - p.z, a.w - p.w);
      }
      ef[f] = v;
    }
  }
  __syncthreads();

  // ---- inner loop: one k-window (3 b128) serves 3 i-values; packed math ----
  f32x2 acc0 = {0.f, 0.f}, acc1 = {0.f, 0.f};
  float accd = 0.f;
#pragma unroll 2
  for (int b = 0; b < BROWS; ++b) {
    float4 vA = *(const float4*)&e_lds[b][k0];
    float4 vB = *(const float4*)&e_lds[b][k0 + 4];
    float4 vC = *(const float4*)&e_lds[b][k0 + 8];
    f32x2 ekp[NP] = {{vA.x, vA.y}, {vA.z, vA.w}, {vB.x, vB.y},
                     {vB.z, vB.w}, {vC.x, vC.y}, {vC.z, vC.w}};
#pragma unroll
    for (int m = 0; m < NI; ++m) {
      float ei = e_lds[b][ig + 32 * m];
      f32x2 ei2 = {ei, ei};
#pragma unroll
      for (int p = 0; p < NP; ++p) {
        f32x2 d = __builtin_elementwise_abs(ei2 - ekp[p]);   // v_pk_add(neg)+2*v_and
        f32x2 inner = __builtin_elementwise_fma(d, w1v[m][p], w0v[m][p]);  // v_pk_fma
        if (p & 1)
          acc1 = __builtin_elementwise_fma(d, inner, acc1);  // v_pk_fma
        else
          acc0 = __builtin_elementwise_fma(d, inner, acc0);
      }
      float a = fabsf(ei);                       // diagonal |e_i| term (scalar)
      accd = fmaf(a, fmaf(a, w1d[m], w0d[m]), accd);
    }
  }
  float acc = acc0.x + acc0.y + acc1.x + acc1.y + accd;

  // ---- reduce 256 threads -> ONE atomic direct to out (R13/R17-proven) ----
#pragma unroll
  for (int off = 32; off; off >>= 1) acc += __shfl_down(acc, off);
  __shared__ float wsum[NT / 64];
  if ((t & 63) == 0) wsum[t >> 6] = acc;
  __syncthreads();
  if (t == 0) {
    float s = wsum[0] + wsum[1] + wsum[2] + wsum[3];
    atomicAdd(out, s * inv_scale);
  }
}

extern "C" void kernel_launch(void* const* d_in, const int* in_sizes, int n_in,
                              void* d_out, int out_size, void* d_ws, size_t ws_size,
                              hipStream_t stream) {
  const float* yt = (const float*)d_in[0];
  const float* yp = (const float*)d_in[1];
  const float* w  = (const float*)d_in[2];
  float* out = (float*)d_out;
  int n = in_sizes[0] / LL;

  dim3 grid((n + BROWS - 1) / BROWS, 1);
  gl_loss_main<<<grid, NT, 0, stream>>>(yt, yp, w, out, n,
                                        1.0f / (float(LL) * float(n)));
}